// Round 11
// baseline (664.969 us; speedup 1.0000x reference)
//
#include <hip/hip_runtime.h>
#include <hip/hip_bf16.h>

#define N_NODES 100000
#define N_EDGES 1600000
#define IN_DIM 64
#define HID 32
#define OUT_DIM 40

#define NBUK 196     // buckets: dst >> 9 (512 nodes each)
#define BCAP 9216    // per-bucket capacity (mean 8163, sigma ~90)
#define BIN_TILE 8192
#define NBIN 196     // bin blocks
#define NLIN 782     // lin1 blocks (128 rows each)

__device__ __forceinline__ float bf2f(unsigned short u) {
    return __uint_as_float(((unsigned int)u) << 16);
}
__device__ __forceinline__ unsigned short f2bf(float f) {
    unsigned int u = __float_as_uint(f);
    u = (u + 0x7fffu + ((u >> 16) & 1u)) >> 16;  // RNE
    return (unsigned short)u;
}

// Detect whether edge_index is stored as int64 (odd dwords all zero) or int32.
// Also zeroes cnt[256].
__global__ void detect_i64(const int* __restrict__ p, int* __restrict__ flagp,
                           int* __restrict__ cnt) {
    __shared__ int s_any;
    if (threadIdx.x == 0) s_any = 0;
    __syncthreads();
    cnt[threadIdx.x] = 0;
    int any = 0;
    for (int i = threadIdx.x; i < 2048; i += blockDim.x) any |= p[2 * i + 1];
    if (any) atomicOr(&s_any, 1);
    __syncthreads();
    if (threadIdx.x == 0) *flagp = (s_any == 0) ? 1 : 0;  // 1 => int64 layout
}

__device__ __forceinline__ int load_idx(const void* ei, int i64, long long pos) {
    if (i64) return (int)((const long long*)ei)[pos];
    return ((const int*)ei)[pos];
}

// Merged kernel: blocks [0,NBIN) bin edges by dst>>9 (packed (src<<9)|(dst&511));
// blocks [NBIN, NBIN+NLIN) compute layer-1 projection (128 rows each).
// The two halves are independent (disjoint inputs/outputs) and co-execute.
__global__ __launch_bounds__(1024) void binlin_kernel(
    const void* __restrict__ ei, const int* __restrict__ flagp,
    int* __restrict__ cnt, int* __restrict__ binned,
    const float* __restrict__ x, const float* __restrict__ Wl,
    const float* __restrict__ Wr, unsigned short* __restrict__ yl,
    unsigned short* __restrict__ yr) {
    __shared__ __align__(16) char smem[49152];
    const int t = threadIdx.x;

    if (blockIdx.x < NBIN) {
        // ---------------- bin path ----------------
        int* si = (int*)smem;
        int* lcount = si;          // [196]
        int* lscan = si + 256;     // [197]
        int* lcur = si + 512;      // [196]
        int* lbase = si + 768;     // [196]
        int* wsum16 = si + 1024;   // [16]
        int* stage = si + 1040;    // [8192]
        if (t < NBUK) lcount[t] = 0;
        __syncthreads();

        const long long e0 = (long long)blockIdx.x * BIN_TILE;
        const int i64 = *flagp;
        int vv[8], bb[8];
#pragma unroll
        for (int k = 0; k < 8; ++k) {
            const long long e = e0 + (long long)k * 1024 + t;
            if (e < N_EDGES) {
                const int s = load_idx(ei, i64, e);
                const int d = load_idx(ei, i64, N_EDGES + e);
                bb[k] = d >> 9;
                vv[k] = (s << 9) | (d & 511);
                atomicAdd(&lcount[bb[k]], 1);
            } else {
                bb[k] = -1;
            }
        }
        __syncthreads();
        // exclusive scan of lcount via wave shfl scans
        const int ival = (t < NBUK) ? lcount[t] : 0;
        const int lane = t & 63;
        const int wid = t >> 6;
        int sv = ival;
#pragma unroll
        for (int off = 1; off < 64; off <<= 1) {
            const int nn = __shfl_up(sv, off, 64);
            if (lane >= off) sv += nn;
        }
        if (lane == 63) wsum16[wid] = sv;
        __syncthreads();
        if (t == 0) {
            int acc = 0;
#pragma unroll
            for (int i = 0; i < 16; ++i) {
                const int v = wsum16[i];
                wsum16[i] = acc;
                acc += v;
            }
        }
        __syncthreads();
        const int incl = sv + wsum16[wid];
        if (t < NBUK) lscan[t] = incl - ival;
        if (t == NBUK - 1) lscan[NBUK] = incl;
        __syncthreads();
        if (t < NBUK) {
            const int c = lcount[t];
            lbase[t] = t * BCAP + (c > 0 ? atomicAdd(&cnt[t], c) : 0);
            lcur[t] = lscan[t];
        }
        __syncthreads();
#pragma unroll
        for (int k = 0; k < 8; ++k) {
            if (bb[k] >= 0) {
                const int pos = atomicAdd(&lcur[bb[k]], 1);
                stage[pos] = vv[k];
            }
        }
        __syncthreads();
        const int total = lscan[NBUK];
        for (int j = t; j < total; j += 1024) {
            int lo = 0, hi = NBUK;
            while (hi - lo > 1) {
                const int mid = (lo + hi) >> 1;
                if (lscan[mid] <= j) lo = mid;
                else hi = mid;
            }
            binned[lbase[lo] + (j - lscan[lo])] = stage[j];
        }
    } else {
        // ---------------- lin1 path (128 rows/block) ----------------
        float* sWl = (float*)smem;       // [2048] 8KB
        float* sWr = sWl + 2048;         // [2048] 8KB
        float* sX = sWl + 4096;          // [8192] 32KB
        for (int i = t; i < IN_DIM * HID; i += 1024) {
            sWl[i] = Wl[i];
            sWr[i] = Wr[i];
        }
        const long long r0 = (long long)(blockIdx.x - NBIN) * 128;
        const int nrows = (int)((N_NODES - r0) < 128 ? (N_NODES - r0) : 128);
        const float4* xv = (const float4*)(x + r0 * IN_DIM);
        float4* sXv = (float4*)sX;
        for (int i = t; i < nrows * 16; i += 1024) sXv[i] = xv[i];
        __syncthreads();

        const int c = t & 31;
        const int rbase = (t >> 5) * 4;  // 32 groups x 4 rows = 128
        float al[4] = {0, 0, 0, 0};
        float ar[4] = {0, 0, 0, 0};
        for (int k = 0; k < IN_DIM; k += 4) {
            const float wl0 = sWl[(k + 0) * HID + c];
            const float wl1 = sWl[(k + 1) * HID + c];
            const float wl2 = sWl[(k + 2) * HID + c];
            const float wl3 = sWl[(k + 3) * HID + c];
            const float wr0 = sWr[(k + 0) * HID + c];
            const float wr1 = sWr[(k + 1) * HID + c];
            const float wr2 = sWr[(k + 2) * HID + c];
            const float wr3 = sWr[(k + 3) * HID + c];
#pragma unroll
            for (int r = 0; r < 4; ++r) {
                const float4 xv4 = *(const float4*)&sX[(rbase + r) * IN_DIM + k];
                al[r] = fmaf(xv4.x, wl0, al[r]);
                al[r] = fmaf(xv4.y, wl1, al[r]);
                al[r] = fmaf(xv4.z, wl2, al[r]);
                al[r] = fmaf(xv4.w, wl3, al[r]);
                ar[r] = fmaf(xv4.x, wr0, ar[r]);
                ar[r] = fmaf(xv4.y, wr1, ar[r]);
                ar[r] = fmaf(xv4.z, wr2, ar[r]);
                ar[r] = fmaf(xv4.w, wr3, ar[r]);
            }
        }
        __syncthreads();
        unsigned short* sB = (unsigned short*)sX;  // 16KB within 32KB, x dead
#pragma unroll
        for (int r = 0; r < 4; ++r) {
            if (rbase + r < nrows) {
                sB[(rbase + r) * HID + c] = f2bf(al[r]);
                sB[4096 + (rbase + r) * HID + c] = f2bf(ar[r]);
            }
        }
        __syncthreads();
        uint4* dl = (uint4*)(yl + r0 * HID);
        uint4* dr = (uint4*)(yr + r0 * HID);
        const uint4* sl = (const uint4*)sB;
        const uint4* sr = (const uint4*)(sB + 4096);
        for (int i = t; i < nrows * 4; i += 1024) {
            dl[i] = sl[i];
            dr[i] = sr[i];
        }
    }
}

// Per-bucket LDS counting sort -> rowstart + csr. Computes its own base
// (bscan folded in via block-wide reduce over cnt[0..b)).
__global__ __launch_bounds__(512) void sort_kernel(const int* __restrict__ cnt,
                                                   const int* __restrict__ binned,
                                                   int* __restrict__ rowstart,
                                                   int* __restrict__ csr) {
    __shared__ int counts[512];
    __shared__ int wsum8[8];
    __shared__ int sbase;
    const int b = blockIdx.x;
    const int t = threadIdx.x;
    const int lane = t & 63;
    const int wid = t >> 6;
    // base = sum cnt[0..b)
    int r = (t < b) ? cnt[t] : 0;
#pragma unroll
    for (int off = 1; off < 64; off <<= 1) r += __shfl_xor(r, off, 64);
    if (lane == 0) wsum8[wid] = r;
    __syncthreads();
    if (t == 0) {
        int s = 0;
#pragma unroll
        for (int i = 0; i < 8; ++i) s += wsum8[i];
        sbase = s;
        if (b == 0) rowstart[N_NODES] = N_EDGES;
    }
    __syncthreads();
    const int base = sbase;
    const int n = cnt[b];
    const int* __restrict__ bin = binned + (long long)b * BCAP;
    counts[t] = 0;
    __syncthreads();
    for (int i = t; i < n; i += 512) atomicAdd(&counts[bin[i] & 511], 1);
    __syncthreads();
    const int v = counts[t];
    int sv = v;
#pragma unroll
    for (int off = 1; off < 64; off <<= 1) {
        const int nn = __shfl_up(sv, off, 64);
        if (lane >= off) sv += nn;
    }
    if (lane == 63) wsum8[wid] = sv;
    __syncthreads();
    if (t == 0) {
        int acc = 0;
#pragma unroll
        for (int i = 0; i < 8; ++i) {
            const int x = wsum8[i];
            wsum8[i] = acc;
            acc += x;
        }
    }
    __syncthreads();
    const int excl = sv + wsum8[wid] - v;
    const int node = b * 512 + t;
    if (node < N_NODES) rowstart[node] = base + excl;
    counts[t] = excl;  // reuse as local cursor
    __syncthreads();
    for (int i = t; i < n; i += 512) {
        const int vv = bin[i];
        const int pos = atomicAdd(&counts[vv & 511], 1);
        csr[base + pos] = vv >> 9;
    }
}

// Per-node gather-mean, 16 lanes/node (2 edge-slots x 8 col-groups), register
// accumulation, 4-deep unroll per slot, shfl fold. Writes
// h = relu(agg/deg + b + yr) into sHrow[q*4..q*4+3].
__device__ __forceinline__ void gather_node16(
    const int* __restrict__ csr, const unsigned short* __restrict__ yl,
    const unsigned short* __restrict__ yr, const float* __restrict__ b,
    int node, int start, int end, int slot, int q, float* sHrow) {
    float ax = 0.f, ay = 0.f, az = 0.f, aw = 0.f;
    const unsigned short* yq = yl + q * 4;
    int e = start + slot;
    for (; e + 6 < end; e += 8) {
        const int s0 = csr[e];
        const int s1 = csr[e + 2];
        const int s2 = csr[e + 4];
        const int s3 = csr[e + 6];
        const ushort4 v0 = *(const ushort4*)(yq + (long long)s0 * HID);
        const ushort4 v1 = *(const ushort4*)(yq + (long long)s1 * HID);
        const ushort4 v2 = *(const ushort4*)(yq + (long long)s2 * HID);
        const ushort4 v3 = *(const ushort4*)(yq + (long long)s3 * HID);
        ax += (bf2f(v0.x) + bf2f(v1.x)) + (bf2f(v2.x) + bf2f(v3.x));
        ay += (bf2f(v0.y) + bf2f(v1.y)) + (bf2f(v2.y) + bf2f(v3.y));
        az += (bf2f(v0.z) + bf2f(v1.z)) + (bf2f(v2.z) + bf2f(v3.z));
        aw += (bf2f(v0.w) + bf2f(v1.w)) + (bf2f(v2.w) + bf2f(v3.w));
    }
    for (; e < end; e += 2) {
        const int s0 = csr[e];
        const ushort4 v0 = *(const ushort4*)(yq + (long long)s0 * HID);
        ax += bf2f(v0.x);
        ay += bf2f(v0.y);
        az += bf2f(v0.z);
        aw += bf2f(v0.w);
    }
    // fold the two slots (lane offset 8 within the 16-lane node group)
    ax += __shfl_xor(ax, 8, 16);
    ay += __shfl_xor(ay, 8, 16);
    az += __shfl_xor(az, 8, 16);
    aw += __shfl_xor(aw, 8, 16);
    if (slot == 0) {
        const float inv = 1.0f / fmaxf((float)(end - start), 1.0f);
        const ushort4 rv = *(const ushort4*)(yr + (long long)node * HID + q * 4);
        const float4 bb = *(const float4*)(b + q * 4);
        sHrow[q * 4 + 0] = fmaxf(fmaf(ax, inv, bb.x) + bf2f(rv.x), 0.f);
        sHrow[q * 4 + 1] = fmaxf(fmaf(ay, inv, bb.y) + bf2f(rv.y), 0.f);
        sHrow[q * 4 + 2] = fmaxf(fmaf(az, inv, bb.z) + bf2f(rv.z), 0.f);
        sHrow[q * 4 + 3] = fmaxf(fmaf(aw, inv, bb.w) + bf2f(rv.w), 0.f);
    }
}

// Fused: gather-mean(Y1l) + combine(Y1r,b1) -> h1 (LDS) -> y2l/y2r = h1 @ W2
__global__ __launch_bounds__(256) void gather_lin2(
    const int* __restrict__ rowstart, const int* __restrict__ csr,
    const unsigned short* __restrict__ yl, const unsigned short* __restrict__ yr,
    const float* __restrict__ b, const float* __restrict__ W2l,
    const float* __restrict__ W2r, unsigned short* __restrict__ y2l,
    unsigned short* __restrict__ y2r) {
    __shared__ float sH[16 * 33];
    __shared__ float sW2l[HID * HID];
    __shared__ float sW2r[HID * HID];
    __shared__ int srow[17];
    const int t = threadIdx.x;
    for (int i = t; i < HID * HID; i += 256) {
        sW2l[i] = W2l[i];
        sW2r[i] = W2r[i];
    }
    const int n0 = blockIdx.x * 16;
    if (t < 17) srow[t] = rowstart[n0 + t];
    __syncthreads();

    const int g = t >> 4;       // node in block (0..15)
    const int sub = t & 15;
    const int slot = sub >> 3;  // edge slot (0..1)
    const int q = sub & 7;      // col group
    const int node = n0 + g;
    gather_node16(csr, yl, yr, b, node, srow[g], srow[g + 1], slot, q,
                  &sH[g * 33]);
    __syncthreads();

    // epilogue GEMM: lane computes cols 2*sub, 2*sub+1 of both mats
    const int c0 = sub * 2;
    float l0 = 0, l1 = 0, m0 = 0, m1 = 0;
#pragma unroll
    for (int k = 0; k < HID; ++k) {
        const float hk = sH[g * 33 + k];
        const float2 wl = *(const float2*)&sW2l[k * HID + c0];
        const float2 wr = *(const float2*)&sW2r[k * HID + c0];
        l0 = fmaf(hk, wl.x, l0);
        l1 = fmaf(hk, wl.y, l1);
        m0 = fmaf(hk, wr.x, m0);
        m1 = fmaf(hk, wr.y, m1);
    }
    ushort2 pl, pr;
    pl.x = f2bf(l0);
    pl.y = f2bf(l1);
    pr.x = f2bf(m0);
    pr.y = f2bf(m1);
    *(ushort2*)(y2l + (long long)node * HID + c0) = pl;
    *(ushort2*)(y2r + (long long)node * HID + c0) = pr;
}

// Fused: gather-mean(Y2l) + combine(Y2r,b2) -> h2 (LDS) -> out = h2 @ w
__global__ __launch_bounds__(256) void gather_out(
    const int* __restrict__ rowstart, const int* __restrict__ csr,
    const unsigned short* __restrict__ yl, const unsigned short* __restrict__ yr,
    const float* __restrict__ b, const float* __restrict__ w,
    float* __restrict__ out) {
    __shared__ float sH[16 * 33];
    __shared__ float sW[HID * OUT_DIM];
    __shared__ int srow[17];
    const int t = threadIdx.x;
    for (int i = t; i < HID * OUT_DIM; i += 256) sW[i] = w[i];
    const int n0 = blockIdx.x * 16;
    if (t < 17) srow[t] = rowstart[n0 + t];
    __syncthreads();

    const int g = t >> 4;
    const int sub = t & 15;
    const int slot = sub >> 3;
    const int q = sub & 7;
    const int node = n0 + g;
    gather_node16(csr, yl, yr, b, node, srow[g], srow[g + 1], slot, q,
                  &sH[g * 33]);
    __syncthreads();

    // epilogue GEMM: lane computes cols sub, sub+16, and (sub<8) sub+32
    const int c2 = (sub < 8) ? (sub + 32) : 0;
    float o0 = 0, o1 = 0, o2 = 0;
#pragma unroll
    for (int k = 0; k < HID; ++k) {
        const float hk = sH[g * 33 + k];
        o0 = fmaf(hk, sW[k * OUT_DIM + sub], o0);
        o1 = fmaf(hk, sW[k * OUT_DIM + sub + 16], o1);
        o2 = fmaf(hk, sW[k * OUT_DIM + c2], o2);
    }
    out[(long long)node * OUT_DIM + sub] = o0;
    out[(long long)node * OUT_DIM + sub + 16] = o1;
    if (sub < 8) out[(long long)node * OUT_DIM + sub + 32] = o2;
}

extern "C" void kernel_launch(void* const* d_in, const int* in_sizes, int n_in,
                              void* d_out, int out_size, void* d_ws,
                              size_t ws_size, hipStream_t stream) {
    const float* x = (const float*)d_in[0];
    const void* ei = d_in[1];
    const float* W1l = (const float*)d_in[2];
    const float* b1 = (const float*)d_in[3];
    const float* W1r = (const float*)d_in[4];
    const float* W2l = (const float*)d_in[5];
    const float* b2 = (const float*)d_in[6];
    const float* W2r = (const float*)d_in[7];
    const float* w = (const float*)d_in[8];
    float* out = (float*)d_out;

    // workspace layout (4-byte units)
    int* ip = (int*)d_ws;
    int* flagp = ip;                        // [64]
    int* cnt = ip + 64;                     // [196] pad 256
    int* rowstart = ip + 320;               // [100001] pad 100032
    int* csr = rowstart + 100032;           // [1600000]
    unsigned short* Y1l = (unsigned short*)(csr + N_EDGES);  // [3.2M bf16]
    unsigned short* Y1r = Y1l + (long long)N_NODES * HID;
    unsigned short* Y2l = Y1r + (long long)N_NODES * HID;
    unsigned short* Y2r = Y2l + (long long)N_NODES * HID;
    // binned aliases Y2l+Y2r (3.2M ints available, need 1.81M): dead after
    // sort_kernel, Y2* written later by gather_lin2 (stream-ordered)
    int* binned = (int*)Y2l;

    // detect kernel also zeroes cnt (no hipMemsetAsync in graph)
    detect_i64<<<1, 256, 0, stream>>>((const int*)ei, flagp, cnt);

    // ---- merged: bin edges (196 blocks) + layer-1 projection (782 blocks) ----
    binlin_kernel<<<NBIN + NLIN, 1024, 0, stream>>>(ei, flagp, cnt, binned, x,
                                                    W1l, W1r, Y1l, Y1r);

    // ---- per-bucket counting sort (computes own base; bscan folded in) ----
    sort_kernel<<<NBUK, 512, 0, stream>>>(cnt, binned, rowstart, csr);

    // ---- fused gather1 + combine + layer-2 projection ----
    gather_lin2<<<N_NODES / 16, 256, 0, stream>>>(rowstart, csr, Y1l, Y1r, b1,
                                                  W2l, W2r, Y2l, Y2r);

    // ---- fused gather2 + combine + output projection ----
    gather_out<<<N_NODES / 16, 256, 0, stream>>>(rowstart, csr, Y2l, Y2r, b2, w,
                                                 out);
}

// Round 12
// 143.178 us; speedup vs baseline: 4.6443x; 4.6443x over previous
//
#include <hip/hip_runtime.h>
#include <hip/hip_bf16.h>

#define N_NODES 100000
#define N_EDGES 1600000
#define IN_DIM 64
#define HID 32
#define OUT_DIM 40

#define NBUK 196     // buckets: dst >> 9 (512 nodes each)
#define BCAP 9216    // per-bucket capacity (mean 8163, sigma ~90)
#define BIN_TILE 8192

__device__ __forceinline__ float bf2f(unsigned short u) {
    return __uint_as_float(((unsigned int)u) << 16);
}
__device__ __forceinline__ unsigned short f2bf(float f) {
    unsigned int u = __float_as_uint(f);
    u = (u + 0x7fffu + ((u >> 16) & 1u)) >> 16;  // RNE
    return (unsigned short)u;
}

// Detect whether edge_index is stored as int64 (odd dwords all zero) or int32.
// Also zeroes cnt[256].
__global__ void detect_i64(const int* __restrict__ p, int* __restrict__ flagp,
                           int* __restrict__ cnt) {
    __shared__ int s_any;
    if (threadIdx.x == 0) s_any = 0;
    __syncthreads();
    cnt[threadIdx.x] = 0;
    int any = 0;
    for (int i = threadIdx.x; i < 2048; i += blockDim.x) any |= p[2 * i + 1];
    if (any) atomicOr(&s_any, 1);
    __syncthreads();
    if (threadIdx.x == 0) *flagp = (s_any == 0) ? 1 : 0;  // 1 => int64 layout
}

__device__ __forceinline__ int load_idx(const void* ei, int i64, long long pos) {
    if (i64) return (int)((const long long*)ei)[pos];
    return ((const int*)ei)[pos];
}

// Pass 1: bin edges by dst>>9 into per-bucket regions, coalesced writes.
// Packed value: (src << 9) | (dst & 511)  -- 26 bits.
__global__ __launch_bounds__(1024) void bin_kernel(const void* __restrict__ ei,
                                                   const int* __restrict__ flagp,
                                                   int* __restrict__ cnt,
                                                   int* __restrict__ binned) {
    __shared__ int lcount[NBUK];
    __shared__ int lscan[NBUK + 1];
    __shared__ int lcur[NBUK];
    __shared__ int lbase[NBUK];
    __shared__ int wsum16[16];
    __shared__ int stage[BIN_TILE];
    const int t = threadIdx.x;
    if (t < NBUK) lcount[t] = 0;
    __syncthreads();

    const long long e0 = (long long)blockIdx.x * BIN_TILE;
    const int i64 = *flagp;
    int vv[8], bb[8];
#pragma unroll
    for (int k = 0; k < 8; ++k) {
        const long long e = e0 + (long long)k * 1024 + t;
        if (e < N_EDGES) {
            const int s = load_idx(ei, i64, e);
            const int d = load_idx(ei, i64, N_EDGES + e);
            bb[k] = d >> 9;
            vv[k] = (s << 9) | (d & 511);
            atomicAdd(&lcount[bb[k]], 1);
        } else {
            bb[k] = -1;
        }
    }
    __syncthreads();
    // exclusive scan of lcount via wave shfl scans (2 barriers)
    const int ival = (t < NBUK) ? lcount[t] : 0;
    const int lane = t & 63;
    const int wid = t >> 6;
    int sv = ival;
#pragma unroll
    for (int off = 1; off < 64; off <<= 1) {
        const int nn = __shfl_up(sv, off, 64);
        if (lane >= off) sv += nn;
    }
    if (lane == 63) wsum16[wid] = sv;
    __syncthreads();
    if (t == 0) {
        int acc = 0;
#pragma unroll
        for (int i = 0; i < 16; ++i) {
            const int x = wsum16[i];
            wsum16[i] = acc;
            acc += x;
        }
    }
    __syncthreads();
    const int incl = sv + wsum16[wid];
    if (t < NBUK) lscan[t] = incl - ival;
    if (t == NBUK - 1) lscan[NBUK] = incl;
    __syncthreads();
    // reserve global runs, init local cursors
    if (t < NBUK) {
        const int c = lcount[t];
        lbase[t] = t * BCAP + (c > 0 ? atomicAdd(&cnt[t], c) : 0);
        lcur[t] = lscan[t];
    }
    __syncthreads();
#pragma unroll
    for (int k = 0; k < 8; ++k) {
        if (bb[k] >= 0) {
            const int pos = atomicAdd(&lcur[bb[k]], 1);
            stage[pos] = vv[k];
        }
    }
    __syncthreads();
    const int total = lscan[NBUK];
    for (int j = t; j < total; j += 1024) {
        int lo = 0, hi = NBUK;
        while (hi - lo > 1) {
            const int mid = (lo + hi) >> 1;
            if (lscan[mid] <= j) lo = mid;
            else hi = mid;
        }
        binned[lbase[lo] + (j - lscan[lo])] = stage[j];
    }
}

// Per-bucket LDS counting sort -> rowstart + csr. Computes its own base
// (bscan folded in via block-wide reduce over cnt[0..b)).
__global__ __launch_bounds__(512) void sort_kernel(const int* __restrict__ cnt,
                                                   const int* __restrict__ binned,
                                                   int* __restrict__ rowstart,
                                                   int* __restrict__ csr) {
    __shared__ int counts[512];
    __shared__ int wsum8[8];
    __shared__ int sbase;
    const int b = blockIdx.x;
    const int t = threadIdx.x;
    const int lane = t & 63;
    const int wid = t >> 6;
    // base = sum cnt[0..b)
    int r = (t < b) ? cnt[t] : 0;
#pragma unroll
    for (int off = 1; off < 64; off <<= 1) r += __shfl_xor(r, off, 64);
    if (lane == 0) wsum8[wid] = r;
    __syncthreads();
    if (t == 0) {
        int s = 0;
#pragma unroll
        for (int i = 0; i < 8; ++i) s += wsum8[i];
        sbase = s;
        if (b == 0) rowstart[N_NODES] = N_EDGES;
    }
    __syncthreads();
    const int base = sbase;
    const int n = cnt[b];
    const int* __restrict__ bin = binned + (long long)b * BCAP;
    counts[t] = 0;
    __syncthreads();
    for (int i = t; i < n; i += 512) atomicAdd(&counts[bin[i] & 511], 1);
    __syncthreads();
    const int v = counts[t];
    int sv = v;
#pragma unroll
    for (int off = 1; off < 64; off <<= 1) {
        const int nn = __shfl_up(sv, off, 64);
        if (lane >= off) sv += nn;
    }
    if (lane == 63) wsum8[wid] = sv;
    __syncthreads();
    if (t == 0) {
        int acc = 0;
#pragma unroll
        for (int i = 0; i < 8; ++i) {
            const int x = wsum8[i];
            wsum8[i] = acc;
            acc += x;
        }
    }
    __syncthreads();
    const int excl = sv + wsum8[wid] - v;
    const int node = b * 512 + t;
    if (node < N_NODES) rowstart[node] = base + excl;
    counts[t] = excl;  // reuse as local cursor
    __syncthreads();
    for (int i = t; i < n; i += 512) {
        const int vv = bin[i];
        const int pos = atomicAdd(&counts[vv & 511], 1);
        csr[base + pos] = vv >> 9;
    }
}

// Layer-1 projection: yl(bf16) = x @ Wl, yr(bf16) = x @ Wr
// 256 threads, 64 rows/block (proven no-spill config).
__global__ __launch_bounds__(256) void lin1_kernel(
    const float* __restrict__ x, const float* __restrict__ Wl,
    const float* __restrict__ Wr, unsigned short* __restrict__ yl,
    unsigned short* __restrict__ yr) {
    __shared__ float sWl[IN_DIM * HID];
    __shared__ float sWr[IN_DIM * HID];
    __shared__ float sX[64 * IN_DIM];
    const int t = threadIdx.x;
    for (int i = t; i < IN_DIM * HID; i += 256) {
        sWl[i] = Wl[i];
        sWr[i] = Wr[i];
    }
    const long long r0 = (long long)blockIdx.x * 64;
    const int nrows = (int)((N_NODES - r0) < 64 ? (N_NODES - r0) : 64);
    const float4* xv = (const float4*)(x + r0 * IN_DIM);
    float4* sXv = (float4*)sX;
    for (int i = t; i < nrows * 16; i += 256) sXv[i] = xv[i];
    __syncthreads();

    const int c = t & 31;
    const int rbase = (t >> 5) * 8;
    float al[8] = {0, 0, 0, 0, 0, 0, 0, 0};
    float ar[8] = {0, 0, 0, 0, 0, 0, 0, 0};
    for (int k = 0; k < IN_DIM; k += 4) {
        const float wl0 = sWl[(k + 0) * HID + c];
        const float wl1 = sWl[(k + 1) * HID + c];
        const float wl2 = sWl[(k + 2) * HID + c];
        const float wl3 = sWl[(k + 3) * HID + c];
        const float wr0 = sWr[(k + 0) * HID + c];
        const float wr1 = sWr[(k + 1) * HID + c];
        const float wr2 = sWr[(k + 2) * HID + c];
        const float wr3 = sWr[(k + 3) * HID + c];
#pragma unroll
        for (int r = 0; r < 8; ++r) {
            const float4 xv4 = *(const float4*)&sX[(rbase + r) * IN_DIM + k];
            al[r] = fmaf(xv4.x, wl0, al[r]);
            al[r] = fmaf(xv4.y, wl1, al[r]);
            al[r] = fmaf(xv4.z, wl2, al[r]);
            al[r] = fmaf(xv4.w, wl3, al[r]);
            ar[r] = fmaf(xv4.x, wr0, ar[r]);
            ar[r] = fmaf(xv4.y, wr1, ar[r]);
            ar[r] = fmaf(xv4.z, wr2, ar[r]);
            ar[r] = fmaf(xv4.w, wr3, ar[r]);
        }
    }
    __syncthreads();
    unsigned short* sB = (unsigned short*)sX;  // 16KB, x is dead
#pragma unroll
    for (int r = 0; r < 8; ++r) {
        if (rbase + r < nrows) {
            sB[(rbase + r) * HID + c] = f2bf(al[r]);
            sB[2048 + (rbase + r) * HID + c] = f2bf(ar[r]);
        }
    }
    __syncthreads();
    uint4* dl = (uint4*)(yl + r0 * HID);
    uint4* dr = (uint4*)(yr + r0 * HID);
    const uint4* sl = (const uint4*)sB;
    const uint4* sr = (const uint4*)(sB + 2048);
    for (int i = t; i < nrows * 4; i += 256) {
        dl[i] = sl[i];
        dr[i] = sr[i];
    }
}

// Per-node gather-mean, 16 lanes/node (2 edge-slots x 8 col-groups), register
// accumulation, 4-deep unroll per slot, shfl fold. Writes
// h = relu(agg/deg + b + yr) into sHrow[q*4..q*4+3].
__device__ __forceinline__ void gather_node16(
    const int* __restrict__ csr, const unsigned short* __restrict__ yl,
    const unsigned short* __restrict__ yr, const float* __restrict__ b,
    int node, int start, int end, int slot, int q, float* sHrow) {
    float ax = 0.f, ay = 0.f, az = 0.f, aw = 0.f;
    const unsigned short* yq = yl + q * 4;
    int e = start + slot;
    for (; e + 6 < end; e += 8) {
        const int s0 = csr[e];
        const int s1 = csr[e + 2];
        const int s2 = csr[e + 4];
        const int s3 = csr[e + 6];
        const ushort4 v0 = *(const ushort4*)(yq + (long long)s0 * HID);
        const ushort4 v1 = *(const ushort4*)(yq + (long long)s1 * HID);
        const ushort4 v2 = *(const ushort4*)(yq + (long long)s2 * HID);
        const ushort4 v3 = *(const ushort4*)(yq + (long long)s3 * HID);
        ax += (bf2f(v0.x) + bf2f(v1.x)) + (bf2f(v2.x) + bf2f(v3.x));
        ay += (bf2f(v0.y) + bf2f(v1.y)) + (bf2f(v2.y) + bf2f(v3.y));
        az += (bf2f(v0.z) + bf2f(v1.z)) + (bf2f(v2.z) + bf2f(v3.z));
        aw += (bf2f(v0.w) + bf2f(v1.w)) + (bf2f(v2.w) + bf2f(v3.w));
    }
    for (; e < end; e += 2) {
        const int s0 = csr[e];
        const ushort4 v0 = *(const ushort4*)(yq + (long long)s0 * HID);
        ax += bf2f(v0.x);
        ay += bf2f(v0.y);
        az += bf2f(v0.z);
        aw += bf2f(v0.w);
    }
    // fold the two slots (lane offset 8 within the 16-lane node group)
    ax += __shfl_xor(ax, 8, 16);
    ay += __shfl_xor(ay, 8, 16);
    az += __shfl_xor(az, 8, 16);
    aw += __shfl_xor(aw, 8, 16);
    if (slot == 0) {
        const float inv = 1.0f / fmaxf((float)(end - start), 1.0f);
        const ushort4 rv = *(const ushort4*)(yr + (long long)node * HID + q * 4);
        const float4 bb = *(const float4*)(b + q * 4);
        sHrow[q * 4 + 0] = fmaxf(fmaf(ax, inv, bb.x) + bf2f(rv.x), 0.f);
        sHrow[q * 4 + 1] = fmaxf(fmaf(ay, inv, bb.y) + bf2f(rv.y), 0.f);
        sHrow[q * 4 + 2] = fmaxf(fmaf(az, inv, bb.z) + bf2f(rv.z), 0.f);
        sHrow[q * 4 + 3] = fmaxf(fmaf(aw, inv, bb.w) + bf2f(rv.w), 0.f);
    }
}

// Fused: gather-mean(Y1l) + combine(Y1r,b1) -> h1 (LDS) -> y2l/y2r = h1 @ W2
__global__ __launch_bounds__(256) void gather_lin2(
    const int* __restrict__ rowstart, const int* __restrict__ csr,
    const unsigned short* __restrict__ yl, const unsigned short* __restrict__ yr,
    const float* __restrict__ b, const float* __restrict__ W2l,
    const float* __restrict__ W2r, unsigned short* __restrict__ y2l,
    unsigned short* __restrict__ y2r) {
    __shared__ float sH[16 * 33];
    __shared__ float sW2l[HID * HID];
    __shared__ float sW2r[HID * HID];
    __shared__ int srow[17];
    const int t = threadIdx.x;
    for (int i = t; i < HID * HID; i += 256) {
        sW2l[i] = W2l[i];
        sW2r[i] = W2r[i];
    }
    const int n0 = blockIdx.x * 16;
    if (t < 17) srow[t] = rowstart[n0 + t];
    __syncthreads();

    const int g = t >> 4;       // node in block (0..15)
    const int sub = t & 15;
    const int slot = sub >> 3;  // edge slot (0..1)
    const int q = sub & 7;      // col group
    const int node = n0 + g;
    gather_node16(csr, yl, yr, b, node, srow[g], srow[g + 1], slot, q,
                  &sH[g * 33]);
    __syncthreads();

    // epilogue GEMM: lane computes cols 2*sub, 2*sub+1 of both mats
    const int c0 = sub * 2;
    float l0 = 0, l1 = 0, m0 = 0, m1 = 0;
#pragma unroll
    for (int k = 0; k < HID; ++k) {
        const float hk = sH[g * 33 + k];
        const float2 wl = *(const float2*)&sW2l[k * HID + c0];
        const float2 wr = *(const float2*)&sW2r[k * HID + c0];
        l0 = fmaf(hk, wl.x, l0);
        l1 = fmaf(hk, wl.y, l1);
        m0 = fmaf(hk, wr.x, m0);
        m1 = fmaf(hk, wr.y, m1);
    }
    ushort2 pl, pr;
    pl.x = f2bf(l0);
    pl.y = f2bf(l1);
    pr.x = f2bf(m0);
    pr.y = f2bf(m1);
    *(ushort2*)(y2l + (long long)node * HID + c0) = pl;
    *(ushort2*)(y2r + (long long)node * HID + c0) = pr;
}

// Fused: gather-mean(Y2l) + combine(Y2r,b2) -> h2 (LDS) -> out = h2 @ w
__global__ __launch_bounds__(256) void gather_out(
    const int* __restrict__ rowstart, const int* __restrict__ csr,
    const unsigned short* __restrict__ yl, const unsigned short* __restrict__ yr,
    const float* __restrict__ b, const float* __restrict__ w,
    float* __restrict__ out) {
    __shared__ float sH[16 * 33];
    __shared__ float sW[HID * OUT_DIM];
    __shared__ int srow[17];
    const int t = threadIdx.x;
    for (int i = t; i < HID * OUT_DIM; i += 256) sW[i] = w[i];
    const int n0 = blockIdx.x * 16;
    if (t < 17) srow[t] = rowstart[n0 + t];
    __syncthreads();

    const int g = t >> 4;
    const int sub = t & 15;
    const int slot = sub >> 3;
    const int q = sub & 7;
    const int node = n0 + g;
    gather_node16(csr, yl, yr, b, node, srow[g], srow[g + 1], slot, q,
                  &sH[g * 33]);
    __syncthreads();

    // epilogue GEMM: lane computes cols sub, sub+16, and (sub<8) sub+32
    const int c2 = (sub < 8) ? (sub + 32) : 0;
    float o0 = 0, o1 = 0, o2 = 0;
#pragma unroll
    for (int k = 0; k < HID; ++k) {
        const float hk = sH[g * 33 + k];
        o0 = fmaf(hk, sW[k * OUT_DIM + sub], o0);
        o1 = fmaf(hk, sW[k * OUT_DIM + sub + 16], o1);
        o2 = fmaf(hk, sW[k * OUT_DIM + c2], o2);
    }
    out[(long long)node * OUT_DIM + sub] = o0;
    out[(long long)node * OUT_DIM + sub + 16] = o1;
    if (sub < 8) out[(long long)node * OUT_DIM + sub + 32] = o2;
}

extern "C" void kernel_launch(void* const* d_in, const int* in_sizes, int n_in,
                              void* d_out, int out_size, void* d_ws,
                              size_t ws_size, hipStream_t stream) {
    const float* x = (const float*)d_in[0];
    const void* ei = d_in[1];
    const float* W1l = (const float*)d_in[2];
    const float* b1 = (const float*)d_in[3];
    const float* W1r = (const float*)d_in[4];
    const float* W2l = (const float*)d_in[5];
    const float* b2 = (const float*)d_in[6];
    const float* W2r = (const float*)d_in[7];
    const float* w = (const float*)d_in[8];
    float* out = (float*)d_out;

    // workspace layout (4-byte units)
    int* ip = (int*)d_ws;
    int* flagp = ip;                        // [64]
    int* cnt = ip + 64;                     // [196] pad 256
    int* rowstart = ip + 320;               // [100001] pad 100032
    int* csr = rowstart + 100032;           // [1600000]
    unsigned short* Y1l = (unsigned short*)(csr + N_EDGES);  // [3.2M bf16]
    unsigned short* Y1r = Y1l + (long long)N_NODES * HID;
    unsigned short* Y2l = Y1r + (long long)N_NODES * HID;
    unsigned short* Y2r = Y2l + (long long)N_NODES * HID;
    // binned aliases Y2l+Y2r (3.2M ints available, need 1.81M): dead after
    // sort_kernel, Y2* written later by gather_lin2 (stream-ordered)
    int* binned = (int*)Y2l;

    // detect kernel also zeroes cnt (no hipMemsetAsync in graph)
    detect_i64<<<1, 256, 0, stream>>>((const int*)ei, flagp, cnt);

    // ---- build CSR: bucket pass + per-bucket counting sort (self-base) ----
    bin_kernel<<<(N_EDGES + BIN_TILE - 1) / BIN_TILE, 1024, 0, stream>>>(
        ei, flagp, cnt, binned);
    sort_kernel<<<NBUK, 512, 0, stream>>>(cnt, binned, rowstart, csr);

    // ---- layer 1 projection (separate 256-thread kernel; no spill) ----
    lin1_kernel<<<(N_NODES + 63) / 64, 256, 0, stream>>>(x, W1l, W1r, Y1l, Y1r);

    // ---- fused gather1 + combine + layer-2 projection ----
    gather_lin2<<<N_NODES / 16, 256, 0, stream>>>(rowstart, csr, Y1l, Y1r, b1,
                                                  W2l, W2r, Y2l, Y2r);

    // ---- fused gather2 + combine + output projection ----
    gather_out<<<N_NODES / 16, 256, 0, stream>>>(rowstart, csr, Y2l, Y2r, b2, w,
                                                 out);
}

// Round 13
// 122.170 us; speedup vs baseline: 5.4430x; 1.1720x over previous
//
#include <hip/hip_runtime.h>
#include <hip/hip_bf16.h>

#define N_NODES 100000
#define N_EDGES 1600000
#define IN_DIM 64
#define HID 32
#define OUT_DIM 40

#define NBUK 196     // buckets: dst >> 9 (512 nodes each)
#define BCAP 9216    // per-bucket capacity (mean 8163, sigma ~90)
#define BIN_TILE 8192

__device__ __forceinline__ float bf2f(unsigned short u) {
    return __uint_as_float(((unsigned int)u) << 16);
}
__device__ __forceinline__ unsigned short f2bf(float f) {
    unsigned int u = __float_as_uint(f);
    u = (u + 0x7fffu + ((u >> 16) & 1u)) >> 16;  // RNE
    return (unsigned short)u;
}

// Detect whether edge_index is stored as int64 (odd dwords all zero) or int32.
// Also zeroes cnt[256].
__global__ void detect_i64(const int* __restrict__ p, int* __restrict__ flagp,
                           int* __restrict__ cnt) {
    __shared__ int s_any;
    if (threadIdx.x == 0) s_any = 0;
    __syncthreads();
    cnt[threadIdx.x] = 0;
    int any = 0;
    for (int i = threadIdx.x; i < 2048; i += blockDim.x) any |= p[2 * i + 1];
    if (any) atomicOr(&s_any, 1);
    __syncthreads();
    if (threadIdx.x == 0) *flagp = (s_any == 0) ? 1 : 0;  // 1 => int64 layout
}

__device__ __forceinline__ int load_idx(const void* ei, int i64, long long pos) {
    if (i64) return (int)((const long long*)ei)[pos];
    return ((const int*)ei)[pos];
}

// Pass 1: bin edges by dst>>9 into per-bucket regions, coalesced writes.
// Packed value: (src << 9) | (dst & 511)  -- 26 bits.
__global__ __launch_bounds__(1024) void bin_kernel(const void* __restrict__ ei,
                                                   const int* __restrict__ flagp,
                                                   int* __restrict__ cnt,
                                                   int* __restrict__ binned) {
    __shared__ int lcount[NBUK];
    __shared__ int lscan[NBUK + 1];
    __shared__ int lcur[NBUK];
    __shared__ int lbase[NBUK];
    __shared__ int wsum16[16];
    __shared__ int stage[BIN_TILE];
    const int t = threadIdx.x;
    if (t < NBUK) lcount[t] = 0;
    __syncthreads();

    const long long e0 = (long long)blockIdx.x * BIN_TILE;
    const int i64 = *flagp;
    int vv[8], bb[8];
#pragma unroll
    for (int k = 0; k < 8; ++k) {
        const long long e = e0 + (long long)k * 1024 + t;
        if (e < N_EDGES) {
            const int s = load_idx(ei, i64, e);
            const int d = load_idx(ei, i64, N_EDGES + e);
            bb[k] = d >> 9;
            vv[k] = (s << 9) | (d & 511);
            atomicAdd(&lcount[bb[k]], 1);
        } else {
            bb[k] = -1;
        }
    }
    __syncthreads();
    // exclusive scan of lcount via wave shfl scans (2 barriers)
    const int ival = (t < NBUK) ? lcount[t] : 0;
    const int lane = t & 63;
    const int wid = t >> 6;
    int sv = ival;
#pragma unroll
    for (int off = 1; off < 64; off <<= 1) {
        const int nn = __shfl_up(sv, off, 64);
        if (lane >= off) sv += nn;
    }
    if (lane == 63) wsum16[wid] = sv;
    __syncthreads();
    if (t == 0) {
        int acc = 0;
#pragma unroll
        for (int i = 0; i < 16; ++i) {
            const int x = wsum16[i];
            wsum16[i] = acc;
            acc += x;
        }
    }
    __syncthreads();
    const int incl = sv + wsum16[wid];
    if (t < NBUK) lscan[t] = incl - ival;
    if (t == NBUK - 1) lscan[NBUK] = incl;
    __syncthreads();
    // reserve global runs, init local cursors
    if (t < NBUK) {
        const int c = lcount[t];
        lbase[t] = t * BCAP + (c > 0 ? atomicAdd(&cnt[t], c) : 0);
        lcur[t] = lscan[t];
    }
    __syncthreads();
#pragma unroll
    for (int k = 0; k < 8; ++k) {
        if (bb[k] >= 0) {
            const int pos = atomicAdd(&lcur[bb[k]], 1);
            stage[pos] = vv[k];
        }
    }
    __syncthreads();
    const int total = lscan[NBUK];
    for (int j = t; j < total; j += 1024) {
        int lo = 0, hi = NBUK;
        while (hi - lo > 1) {
            const int mid = (lo + hi) >> 1;
            if (lscan[mid] <= j) lo = mid;
            else hi = mid;
        }
        binned[lbase[lo] + (j - lscan[lo])] = stage[j];
    }
}

// Per-bucket LDS counting sort -> rowstart + csr. Computes its own base
// (bscan folded in via block-wide reduce over cnt[0..b)).
__global__ __launch_bounds__(512) void sort_kernel(const int* __restrict__ cnt,
                                                   const int* __restrict__ binned,
                                                   int* __restrict__ rowstart,
                                                   int* __restrict__ csr) {
    __shared__ int counts[512];
    __shared__ int wsum8[8];
    __shared__ int sbase;
    const int b = blockIdx.x;
    const int t = threadIdx.x;
    const int lane = t & 63;
    const int wid = t >> 6;
    // base = sum cnt[0..b)
    int r = (t < b) ? cnt[t] : 0;
#pragma unroll
    for (int off = 1; off < 64; off <<= 1) r += __shfl_xor(r, off, 64);
    if (lane == 0) wsum8[wid] = r;
    __syncthreads();
    if (t == 0) {
        int s = 0;
#pragma unroll
        for (int i = 0; i < 8; ++i) s += wsum8[i];
        sbase = s;
        if (b == 0) rowstart[N_NODES] = N_EDGES;
    }
    __syncthreads();
    const int base = sbase;
    const int n = cnt[b];
    const int* __restrict__ bin = binned + (long long)b * BCAP;
    counts[t] = 0;
    __syncthreads();
    for (int i = t; i < n; i += 512) atomicAdd(&counts[bin[i] & 511], 1);
    __syncthreads();
    const int v = counts[t];
    int sv = v;
#pragma unroll
    for (int off = 1; off < 64; off <<= 1) {
        const int nn = __shfl_up(sv, off, 64);
        if (lane >= off) sv += nn;
    }
    if (lane == 63) wsum8[wid] = sv;
    __syncthreads();
    if (t == 0) {
        int acc = 0;
#pragma unroll
        for (int i = 0; i < 8; ++i) {
            const int x = wsum8[i];
            wsum8[i] = acc;
            acc += x;
        }
    }
    __syncthreads();
    const int excl = sv + wsum8[wid] - v;
    const int node = b * 512 + t;
    if (node < N_NODES) rowstart[node] = base + excl;
    counts[t] = excl;  // reuse as local cursor
    __syncthreads();
    for (int i = t; i < n; i += 512) {
        const int vv = bin[i];
        const int pos = atomicAdd(&counts[vv & 511], 1);
        csr[base + pos] = vv >> 9;
    }
}

// Layer-1 projection: yl(bf16) = x @ Wl, yr(bf16) = x @ Wr
// 256 threads, 64 rows/block (proven no-spill config).
__global__ __launch_bounds__(256) void lin1_kernel(
    const float* __restrict__ x, const float* __restrict__ Wl,
    const float* __restrict__ Wr, unsigned short* __restrict__ yl,
    unsigned short* __restrict__ yr) {
    __shared__ float sWl[IN_DIM * HID];
    __shared__ float sWr[IN_DIM * HID];
    __shared__ float sX[64 * IN_DIM];
    const int t = threadIdx.x;
    for (int i = t; i < IN_DIM * HID; i += 256) {
        sWl[i] = Wl[i];
        sWr[i] = Wr[i];
    }
    const long long r0 = (long long)blockIdx.x * 64;
    const int nrows = (int)((N_NODES - r0) < 64 ? (N_NODES - r0) : 64);
    const float4* xv = (const float4*)(x + r0 * IN_DIM);
    float4* sXv = (float4*)sX;
    for (int i = t; i < nrows * 16; i += 256) sXv[i] = xv[i];
    __syncthreads();

    const int c = t & 31;
    const int rbase = (t >> 5) * 8;
    float al[8] = {0, 0, 0, 0, 0, 0, 0, 0};
    float ar[8] = {0, 0, 0, 0, 0, 0, 0, 0};
    for (int k = 0; k < IN_DIM; k += 4) {
        const float wl0 = sWl[(k + 0) * HID + c];
        const float wl1 = sWl[(k + 1) * HID + c];
        const float wl2 = sWl[(k + 2) * HID + c];
        const float wl3 = sWl[(k + 3) * HID + c];
        const float wr0 = sWr[(k + 0) * HID + c];
        const float wr1 = sWr[(k + 1) * HID + c];
        const float wr2 = sWr[(k + 2) * HID + c];
        const float wr3 = sWr[(k + 3) * HID + c];
#pragma unroll
        for (int r = 0; r < 8; ++r) {
            const float4 xv4 = *(const float4*)&sX[(rbase + r) * IN_DIM + k];
            al[r] = fmaf(xv4.x, wl0, al[r]);
            al[r] = fmaf(xv4.y, wl1, al[r]);
            al[r] = fmaf(xv4.z, wl2, al[r]);
            al[r] = fmaf(xv4.w, wl3, al[r]);
            ar[r] = fmaf(xv4.x, wr0, ar[r]);
            ar[r] = fmaf(xv4.y, wr1, ar[r]);
            ar[r] = fmaf(xv4.z, wr2, ar[r]);
            ar[r] = fmaf(xv4.w, wr3, ar[r]);
        }
    }
    __syncthreads();
    unsigned short* sB = (unsigned short*)sX;  // 16KB, x is dead
#pragma unroll
    for (int r = 0; r < 8; ++r) {
        if (rbase + r < nrows) {
            sB[(rbase + r) * HID + c] = f2bf(al[r]);
            sB[2048 + (rbase + r) * HID + c] = f2bf(ar[r]);
        }
    }
    __syncthreads();
    uint4* dl = (uint4*)(yl + r0 * HID);
    uint4* dr = (uint4*)(yr + r0 * HID);
    const uint4* sl = (const uint4*)sB;
    const uint4* sr = (const uint4*)(sB + 2048);
    for (int i = t; i < nrows * 4; i += 256) {
        dl[i] = sl[i];
        dr[i] = sr[i];
    }
}

// Per-node gather-mean, 8 lanes/node, register accumulation, 8-deep unroll.
// Writes h = relu(agg/deg + b + yr) into sHrow[q*4..q*4+3].
__device__ __forceinline__ void gather_node8(
    const int* __restrict__ csr, const unsigned short* __restrict__ yl,
    const unsigned short* __restrict__ yr, const float* __restrict__ b,
    int node, int start, int end, int q, float* sHrow) {
    float ax = 0.f, ay = 0.f, az = 0.f, aw = 0.f;
    const unsigned short* yq = yl + q * 4;
    int e = start;
    for (; e + 7 < end; e += 8) {
        int s[8];
#pragma unroll
        for (int j = 0; j < 8; ++j) s[j] = csr[e + j];
        ushort4 v[8];
#pragma unroll
        for (int j = 0; j < 8; ++j)
            v[j] = *(const ushort4*)(yq + (long long)s[j] * HID);
#pragma unroll
        for (int j = 0; j < 8; ++j) {
            ax += bf2f(v[j].x);
            ay += bf2f(v[j].y);
            az += bf2f(v[j].z);
            aw += bf2f(v[j].w);
        }
    }
    if (e + 3 < end) {
        int s[4];
#pragma unroll
        for (int j = 0; j < 4; ++j) s[j] = csr[e + j];
#pragma unroll
        for (int j = 0; j < 4; ++j) {
            const ushort4 v = *(const ushort4*)(yq + (long long)s[j] * HID);
            ax += bf2f(v.x);
            ay += bf2f(v.y);
            az += bf2f(v.z);
            aw += bf2f(v.w);
        }
        e += 4;
    }
    if (e + 1 < end) {
        const int s0 = csr[e];
        const int s1 = csr[e + 1];
        const ushort4 v0 = *(const ushort4*)(yq + (long long)s0 * HID);
        const ushort4 v1 = *(const ushort4*)(yq + (long long)s1 * HID);
        ax += bf2f(v0.x) + bf2f(v1.x);
        ay += bf2f(v0.y) + bf2f(v1.y);
        az += bf2f(v0.z) + bf2f(v1.z);
        aw += bf2f(v0.w) + bf2f(v1.w);
        e += 2;
    }
    if (e < end) {
        const int s0 = csr[e];
        const ushort4 v0 = *(const ushort4*)(yq + (long long)s0 * HID);
        ax += bf2f(v0.x);
        ay += bf2f(v0.y);
        az += bf2f(v0.z);
        aw += bf2f(v0.w);
    }
    const float inv = 1.0f / fmaxf((float)(end - start), 1.0f);
    const ushort4 rv = *(const ushort4*)(yr + (long long)node * HID + q * 4);
    const float4 bb = *(const float4*)(b + q * 4);
    sHrow[q * 4 + 0] = fmaxf(fmaf(ax, inv, bb.x) + bf2f(rv.x), 0.f);
    sHrow[q * 4 + 1] = fmaxf(fmaf(ay, inv, bb.y) + bf2f(rv.y), 0.f);
    sHrow[q * 4 + 2] = fmaxf(fmaf(az, inv, bb.z) + bf2f(rv.z), 0.f);
    sHrow[q * 4 + 3] = fmaxf(fmaf(aw, inv, bb.w) + bf2f(rv.w), 0.f);
}

// Fused: gather-mean(Y1l) + combine(Y1r,b1) -> h1 (LDS) -> y2l/y2r = h1 @ W2
__global__ __launch_bounds__(256) void gather_lin2(
    const int* __restrict__ rowstart, const int* __restrict__ csr,
    const unsigned short* __restrict__ yl, const unsigned short* __restrict__ yr,
    const float* __restrict__ b, const float* __restrict__ W2l,
    const float* __restrict__ W2r, unsigned short* __restrict__ y2l,
    unsigned short* __restrict__ y2r) {
    __shared__ float sH[32 * 33];
    __shared__ float sW2l[HID * HID];
    __shared__ float sW2r[HID * HID];
    __shared__ int srow[33];
    const int t = threadIdx.x;
    for (int i = t; i < HID * HID; i += 256) {
        sW2l[i] = W2l[i];
        sW2r[i] = W2r[i];
    }
    const int n0 = blockIdx.x * 32;
    if (t < 33) srow[t] = rowstart[n0 + t];
    __syncthreads();

    const int ln = t >> 3;
    const int q = t & 7;
    const int node = n0 + ln;
    gather_node8(csr, yl, yr, b, node, srow[ln], srow[ln + 1], q, &sH[ln * 33]);
    __syncthreads();

    float l0 = 0, l1 = 0, l2 = 0, l3 = 0, m0 = 0, m1 = 0, m2 = 0, m3 = 0;
#pragma unroll
    for (int k = 0; k < HID; ++k) {
        const float hk = sH[ln * 33 + k];
        const float4 wl = *(const float4*)&sW2l[k * HID + q * 4];
        const float4 wr = *(const float4*)&sW2r[k * HID + q * 4];
        l0 = fmaf(hk, wl.x, l0);
        l1 = fmaf(hk, wl.y, l1);
        l2 = fmaf(hk, wl.z, l2);
        l3 = fmaf(hk, wl.w, l3);
        m0 = fmaf(hk, wr.x, m0);
        m1 = fmaf(hk, wr.y, m1);
        m2 = fmaf(hk, wr.z, m2);
        m3 = fmaf(hk, wr.w, m3);
    }
    ushort4 pl, pr;
    pl.x = f2bf(l0);
    pl.y = f2bf(l1);
    pl.z = f2bf(l2);
    pl.w = f2bf(l3);
    pr.x = f2bf(m0);
    pr.y = f2bf(m1);
    pr.z = f2bf(m2);
    pr.w = f2bf(m3);
    *(ushort4*)(y2l + (long long)node * HID + q * 4) = pl;
    *(ushort4*)(y2r + (long long)node * HID + q * 4) = pr;
}

// Fused: gather-mean(Y2l) + combine(Y2r,b2) -> h2 (LDS) -> out = h2 @ w
__global__ __launch_bounds__(256) void gather_out(
    const int* __restrict__ rowstart, const int* __restrict__ csr,
    const unsigned short* __restrict__ yl, const unsigned short* __restrict__ yr,
    const float* __restrict__ b, const float* __restrict__ w,
    float* __restrict__ out) {
    __shared__ float sH[32 * 33];
    __shared__ float sW[HID * OUT_DIM];
    __shared__ int srow[33];
    const int t = threadIdx.x;
    for (int i = t; i < HID * OUT_DIM; i += 256) sW[i] = w[i];
    const int n0 = blockIdx.x * 32;
    if (t < 33) srow[t] = rowstart[n0 + t];
    __syncthreads();

    const int ln = t >> 3;
    const int q = t & 7;
    const int node = n0 + ln;
    gather_node8(csr, yl, yr, b, node, srow[ln], srow[ln + 1], q, &sH[ln * 33]);
    __syncthreads();

    float o[5] = {0, 0, 0, 0, 0};
#pragma unroll
    for (int k = 0; k < HID; ++k) {
        const float hk = sH[ln * 33 + k];
#pragma unroll
        for (int j = 0; j < 5; ++j)
            o[j] = fmaf(hk, sW[k * OUT_DIM + q + 8 * j], o[j]);
    }
#pragma unroll
    for (int j = 0; j < 5; ++j) out[(long long)node * OUT_DIM + q + 8 * j] = o[j];
}

extern "C" void kernel_launch(void* const* d_in, const int* in_sizes, int n_in,
                              void* d_out, int out_size, void* d_ws,
                              size_t ws_size, hipStream_t stream) {
    const float* x = (const float*)d_in[0];
    const void* ei = d_in[1];
    const float* W1l = (const float*)d_in[2];
    const float* b1 = (const float*)d_in[3];
    const float* W1r = (const float*)d_in[4];
    const float* W2l = (const float*)d_in[5];
    const float* b2 = (const float*)d_in[6];
    const float* W2r = (const float*)d_in[7];
    const float* w = (const float*)d_in[8];
    float* out = (float*)d_out;

    // workspace layout (4-byte units)
    int* ip = (int*)d_ws;
    int* flagp = ip;                        // [64]
    int* cnt = ip + 64;                     // [196] pad 256
    int* rowstart = ip + 320;               // [100001] pad 100032
    int* csr = rowstart + 100032;           // [1600000]
    unsigned short* Y1l = (unsigned short*)(csr + N_EDGES);  // [3.2M bf16]
    unsigned short* Y1r = Y1l + (long long)N_NODES * HID;
    unsigned short* Y2l = Y1r + (long long)N_NODES * HID;
    unsigned short* Y2r = Y2l + (long long)N_NODES * HID;
    // binned aliases Y2l+Y2r (3.2M ints available, need 1.81M): dead after
    // sort_kernel, Y2* written later by gather_lin2 (stream-ordered)
    int* binned = (int*)Y2l;

    // detect kernel also zeroes cnt (no hipMemsetAsync in graph)
    detect_i64<<<1, 256, 0, stream>>>((const int*)ei, flagp, cnt);

    // ---- build CSR: bucket pass + per-bucket counting sort (self-base) ----
    bin_kernel<<<(N_EDGES + BIN_TILE - 1) / BIN_TILE, 1024, 0, stream>>>(
        ei, flagp, cnt, binned);
    sort_kernel<<<NBUK, 512, 0, stream>>>(cnt, binned, rowstart, csr);

    // ---- layer 1 projection (256 threads, 64 rows; no spill) ----
    lin1_kernel<<<(N_NODES + 63) / 64, 256, 0, stream>>>(x, W1l, W1r, Y1l, Y1r);

    // ---- fused gather1 + combine + layer-2 projection ----
    gather_lin2<<<(N_NODES + 31) / 32, 256, 0, stream>>>(rowstart, csr, Y1l,
                                                         Y1r, b1, W2l, W2r,
                                                         Y2l, Y2r);

    // ---- fused gather2 + combine + output projection ----
    gather_out<<<(N_NODES + 31) / 32, 256, 0, stream>>>(rowstart, csr, Y2l, Y2r,
                                                        b2, w, out);
}